// Round 6
// baseline (129.055 us; speedup 1.0000x reference)
//
#include <hip/hip_runtime.h>

// B=32, C=8, L=2048, K=512, S=64, W=1985
// out[b,0,q] = max(0, max_w sum_c dot(xw_n[b,c,w,:], sn_n[c,q,:]) / 8)

#define B_ 32
#define C_ 8
#define L_ 2048
#define K_ 512
#define S_ 64
#define W_ 1985
#define TW 128                        // windows per block tile

typedef _Float16 f16x8 __attribute__((ext_vector_type(8)));
typedef float f32x16 __attribute__((ext_vector_type(16)));
typedef float f32x4u __attribute__((ext_vector_type(4), aligned(4)));

// ---- prologue: pack shapelets in 32x32x16 B-frag layout + zero out ----
// Bp unit ((c*4+kq)*16 + nt)*64 + lane:
//   value[j] = sn_norm[c][nt*32 + (lane&31)][kq*16 + (lane>>5)*8 + j]
__global__ __launch_bounds__(256)
void prep_k(const float* __restrict__ sh, _Float16* __restrict__ Bp,
            float* __restrict__ out) {
    const int tid = threadIdx.x;
    const int blk = blockIdx.x;
    int gid = blk * 256 + tid;
    if (gid < B_ * K_) out[gid] = 0.f;

    const int sb   = blk * 4 + (tid >> 6);   // 0..511 = c(8) x kq(4) x nt(16)
    const int c    = sb >> 6;
    const int kq   = (sb >> 4) & 3;
    const int nt   = sb & 15;
    const int lane = tid & 63;
    const int half = lane >> 5;
    const int q    = nt * 32 + (lane & 31);

    const float4* sp = (const float4*)(sh + (size_t)(c * K_ + q) * S_);
    float ss = 0.f;
    #pragma unroll
    for (int i = 0; i < 8; ++i) {
        float4 v = sp[half * 8 + i];
        ss += v.x * v.x + v.y * v.y + v.z * v.z + v.w * v.w;
    }
    ss += __shfl_xor(ss, 32);
    float inv = 1.f / fmaxf(sqrtf(ss), 1e-8f);

    float4 u0 = sp[kq * 4 + half * 2];
    float4 u1 = sp[kq * 4 + half * 2 + 1];
    f16x8 o;
    o[0] = (_Float16)(u0.x * inv); o[1] = (_Float16)(u0.y * inv);
    o[2] = (_Float16)(u0.z * inv); o[3] = (_Float16)(u0.w * inv);
    o[4] = (_Float16)(u1.x * inv); o[5] = (_Float16)(u1.y * inv);
    o[6] = (_Float16)(u1.z * inv); o[7] = (_Float16)(u1.w * inv);
    ((f16x8*)Bp)[((c * 4 + kq) * 16 + nt) * 64 + lane] = o;
}

// ---- main: 32x32x16 MFMA GEMM + relu + max ----
// grid (16 wt, 4 ng, 32 b), 256 threads = 4 waves (mg x nw = 2x2).
// Block: 128 windows x 128 cols. Wave: 64 windows (mt=2) x 64 cols (nt=2).
// acc 2x2xf32x16 = 64 regs; full-channel B prefetch (8 frags = 64 regs).
__global__ __launch_bounds__(256, 2)
void mcs_k(const float* __restrict__ x, const _Float16* __restrict__ Bp,
           float* __restrict__ out) {
    __shared__ float invs[C_ * TW];      // 4 KB
    __shared__ f16x8 Ah[2][16 * 64];     // 32 KB: 16 frags (mg2 x mt2 x ks4)

    const int wt  = blockIdx.x;
    const int ng  = blockIdx.y;
    const int b   = blockIdx.z;
    const int w0  = wt * TW;
    const int tid = threadIdx.x;
    const int lane = tid & 63;
    const int wv   = tid >> 6;
    const int mg   = wv >> 1;
    const int nw   = wv & 1;

    // ---- window inv-norms via per-thread sliding sum (4 windows each) ----
    {
        const int c  = tid >> 5;          // 0..7
        const int g  = tid & 31;          // 0..31
        const int wb = w0 + g * 4;
        const float* xr = x + (size_t)(b * C_ + c) * L_;
        float ss = 0.f;
        #pragma unroll
        for (int j = 0; j < S_; ++j) {
            int idx = wb + j;
            float v = idx < L_ ? xr[idx] : 0.f;
            ss += v * v;
        }
        #pragma unroll
        for (int u = 0; u < 4; ++u) {
            int w = wb + u;
            invs[c * TW + g * 4 + u] =
                (w < W_) ? 0.125f / fmaxf(sqrtf(ss), 1e-8f) : 0.f;
            float pv = xr[w];                      // w <= 2047 always
            int ni = w + S_;
            float nv = ni < L_ ? xr[ni] : 0.f;
            ss += nv * nv - pv * pv;
        }
    }

    // build channel cN's A-frags into Ah[bufN] (global reads, inv-scaled)
    // frag f = mg*8 + mt*4 + ks; lane l: A[m = mg*64+mt*32+(l&31)]
    //   [k = ks*16 + (l>>5)*8 + j] = x[c][w0+m + ks*16+(l>>5)*8+j] * iv[m]
    auto build = [&](int cN, int bufN) {
        const float* xrow = x + (size_t)(b * C_ + cN) * L_;
        #pragma unroll
        for (int it = 0; it < 4; ++it) {
            int i  = tid + it * 256;        // 0..1023
            int f  = i >> 6, l = i & 63;
            int mgb = f >> 3, mt = (f >> 2) & 1, ks = f & 3;
            int m  = mgb * 64 + mt * 32 + (l & 31);
            int p  = w0 + m + ks * 16 + (l >> 5) * 8;
            int pc = p <= L_ - 8 ? p : L_ - 8;   // only invalid windows clamp
            f32x4u v0 = *(const f32x4u*)(xrow + pc);
            f32x4u v1 = *(const f32x4u*)(xrow + pc + 4);
            float iv = invs[cN * TW + m];         // 0 for invalid windows
            f16x8 o;
            o[0] = (_Float16)(v0[0] * iv); o[1] = (_Float16)(v0[1] * iv);
            o[2] = (_Float16)(v0[2] * iv); o[3] = (_Float16)(v0[3] * iv);
            o[4] = (_Float16)(v1[0] * iv); o[5] = (_Float16)(v1[1] * iv);
            o[6] = (_Float16)(v1[2] * iv); o[7] = (_Float16)(v1[3] * iv);
            Ah[bufN][f * 64 + l] = o;
        }
    };

    __syncthreads();            // invs ready
    build(0, 0);
    __syncthreads();            // Ah[0] ready

    f32x16 acc[2][2];
    #pragma unroll
    for (int mt = 0; mt < 2; ++mt)
        #pragma unroll
        for (int nt = 0; nt < 2; ++nt)
            #pragma unroll
            for (int r = 0; r < 16; ++r) acc[mt][nt][r] = 0.f;

    #pragma unroll 1
    for (int c = 0; c < C_; ++c) {
        const int buf = c & 1;

        // explicit full-channel B prefetch: 8 frags = 64 VGPRs in flight
        f16x8 bfr[4][2];
        {
            const f16x8* bbase = (const f16x8*)Bp +
                ((c * 4) * 16 + ng * 4 + nw * 2) * 64 + lane;
            #pragma unroll
            for (int ks = 0; ks < 4; ++ks)
                #pragma unroll
                for (int nt = 0; nt < 2; ++nt)
                    bfr[ks][nt] = bbase[(ks * 16 + nt) * 64];
        }

        if (c + 1 < C_) build(c + 1, buf ^ 1);   // overlap next-channel build

        #pragma unroll
        for (int ks = 0; ks < 4; ++ks) {
            f16x8 af[2];
            af[0] = Ah[buf][(mg * 8 + ks) * 64 + lane];
            af[1] = Ah[buf][(mg * 8 + 4 + ks) * 64 + lane];
            #pragma unroll
            for (int nt = 0; nt < 2; ++nt)
                #pragma unroll
                for (int mt = 0; mt < 2; ++mt)
                    acc[mt][nt] = __builtin_amdgcn_mfma_f32_32x32x16_f16(
                        af[mt], bfr[ks][nt], acc[mt][nt], 0, 0, 0);
        }
        __syncthreads();        // consume(c) done + Ah[buf^1] written
    }

    // epilogue: relu + max over windows (invalid windows exactly 0).
    // 32x32 C/D: col = lane&31 -> lane and lane^32 cover same col.
    #pragma unroll
    for (int nt = 0; nt < 2; ++nt) {
        float m = 0.f;
        #pragma unroll
        for (int mt = 0; mt < 2; ++mt)
            #pragma unroll
            for (int r = 0; r < 16; ++r)
                m = fmaxf(m, acc[mt][nt][r]);
        m = fmaxf(m, __shfl_xor(m, 32));
        if (lane < 32)
            atomicMax((unsigned int*)(out + b * K_ + ng * 128 + nw * 64 + nt * 32 + lane),
                      __float_as_uint(m));
    }
}

extern "C" void kernel_launch(void* const* d_in, const int* in_sizes, int n_in,
                              void* d_out, int out_size, void* d_ws, size_t ws_size,
                              hipStream_t stream) {
    const float* x  = (const float*)d_in[0];   // (32, 8, 2048) fp32
    const float* sh = (const float*)d_in[1];   // (8, 512, 64) fp32
    float* out = (float*)d_out;                // (32, 1, 512) fp32
    _Float16* Bp  = (_Float16*)d_ws;           // 512 KB packed shapelets

    prep_k<<<dim3(128), dim3(256), 0, stream>>>(sh, Bp, out);
    mcs_k<<<dim3(16, 4, B_), dim3(256), 0, stream>>>(x, Bp, out);
}

// Round 7
// 99.525 us; speedup vs baseline: 1.2967x; 1.2967x over previous
//
#include <hip/hip_runtime.h>

// B=32, C=8, L=2048, K=512, S=64, W=1985
// out[b,0,q] = max(0, max_w sum_c dot(xw_n[b,c,w,:], sn_n[c,q,:]) / 8)

#define B_ 32
#define C_ 8
#define L_ 2048
#define K_ 512
#define S_ 64
#define W_ 1985
#define TW 128                        // windows per block tile

typedef _Float16 f16x8 __attribute__((ext_vector_type(8)));
typedef float f32x16 __attribute__((ext_vector_type(16)));
typedef float f32x4u __attribute__((ext_vector_type(4), aligned(4)));

// ---- prologue: pack shapelets (blocks 0..127) in 32x32x16 B-frag layout,
//      window inv-norms (blocks 128..383) + zero out ----
// Bp unit ((c*4+kq)*16 + nt)*64 + lane:
//   value[j] = sn_norm[c][nt*32 + (lane&31)][kq*16 + (lane>>5)*8 + j]
__global__ __launch_bounds__(256)
void prep_k(const float* __restrict__ x, const float* __restrict__ sh,
            _Float16* __restrict__ Bp, float* __restrict__ invn,
            float* __restrict__ out) {
    __shared__ float xr[L_];             // norm blocks only
    const int tid = threadIdx.x;
    const int blk = blockIdx.x;

    if (blk < 128) {
        const int sb   = blk * 4 + (tid >> 6);   // 0..511 = c(8) x kq(4) x nt(16)
        const int c    = sb >> 6;
        const int kq   = (sb >> 4) & 3;
        const int nt   = sb & 15;
        const int lane = tid & 63;
        const int half = lane >> 5;
        const int q    = nt * 32 + (lane & 31);

        const float4* sp = (const float4*)(sh + (size_t)(c * K_ + q) * S_);
        float ss = 0.f;
        #pragma unroll
        for (int i = 0; i < 8; ++i) {
            float4 v = sp[half * 8 + i];
            ss += v.x * v.x + v.y * v.y + v.z * v.z + v.w * v.w;
        }
        ss += __shfl_xor(ss, 32);
        float inv = 1.f / fmaxf(sqrtf(ss), 1e-8f);

        float4 u0 = sp[kq * 4 + half * 2];
        float4 u1 = sp[kq * 4 + half * 2 + 1];
        f16x8 o;
        o[0] = (_Float16)(u0.x * inv); o[1] = (_Float16)(u0.y * inv);
        o[2] = (_Float16)(u0.z * inv); o[3] = (_Float16)(u0.w * inv);
        o[4] = (_Float16)(u1.x * inv); o[5] = (_Float16)(u1.y * inv);
        o[6] = (_Float16)(u1.z * inv); o[7] = (_Float16)(u1.w * inv);
        ((f16x8*)Bp)[((c * 4 + kq) * 16 + nt) * 64 + lane] = o;
    } else {
        // window inverse norms for row r = b*8+c via sliding sum
        const int r = blk - 128;             // 0..255
        const float* xp = x + (size_t)r * L_;
        for (int i = tid; i < L_ / 4; i += 256)
            ((float4*)xr)[i] = ((const float4*)xp)[i];
        __syncthreads();

        float* ivp = invn + (size_t)r * L_;
        const int w0 = tid * 8;
        float ss = 0.f;
        if (w0 < W_) {
            #pragma unroll
            for (int j = 0; j < S_; ++j) { float v = xr[w0 + j]; ss += v * v; }
        }
        #pragma unroll
        for (int u = 0; u < 8; ++u) {
            int w = w0 + u;
            float o = 0.f;
            if (u > 0 && w < W_)
                ss += xr[w + 63] * xr[w + 63] - xr[w - 1] * xr[w - 1];
            if (w < W_) o = 0.125f / fmaxf(sqrtf(ss), 1e-8f);
            if (w < L_) ivp[w] = o;
        }
        if (r < 64) out[r * 256 + tid] = 0.f;   // zero output
    }
}

// ---- main: barrier-free per-wave MFMA GEMM + relu + max ----
// grid (16 wt, 2 ng, 32 b) = 1024 blocks, 256 threads = 4 independent waves.
// Wave (mg,nw): 64 windows (mt=2 x 32) x 128 cols (nt=4 x 32).
// A-frags built in registers straight from global x (L1-hot, 8 consecutive
// floats/lane); no LDS, no __syncthreads. acc = 2x4 x f32x16 = 128 AGPRs.
__global__ __launch_bounds__(256, 2)
void mcs_k(const float* __restrict__ x, const _Float16* __restrict__ Bp,
           const float* __restrict__ invn, float* __restrict__ out) {
    const int wt  = blockIdx.x;
    const int ng  = blockIdx.y;
    const int b   = blockIdx.z;
    const int tid = threadIdx.x;
    const int lane = tid & 63;
    const int wv   = tid >> 6;
    const int mg   = wv >> 1;
    const int nw   = wv & 1;

    const int l31 = lane & 31;
    const int lh  = lane >> 5;
    const int Wb  = wt * TW + mg * 64;    // wave's window base
    const int m0  = Wb + l31;             // lane's two window rows
    const int m1  = Wb + 32 + l31;

    f32x16 acc[2][4];
    #pragma unroll
    for (int mt = 0; mt < 2; ++mt)
        #pragma unroll
        for (int nt = 0; nt < 4; ++nt)
            #pragma unroll
            for (int r = 0; r < 16; ++r) acc[mt][nt][r] = 0.f;

    #pragma unroll 1
    for (int c = 0; c < C_; ++c) {
        const float* ivp  = invn + (size_t)(b * C_ + c) * L_;
        const float* xrow = x + (size_t)(b * C_ + c) * L_;
        float iv0 = ivp[m0];              // 0 for invalid windows
        float iv1 = ivp[m1];

        // B fragments: 16 x dwordx4 from packed L2-resident Bp
        const f16x8* bbase = (const f16x8*)Bp +
            ((c * 4) * 16 + ng * 8 + nw * 4) * 64 + lane;
        f16x8 bfr[4][4];
        #pragma unroll
        for (int ks = 0; ks < 4; ++ks)
            #pragma unroll
            for (int nt = 0; nt < 4; ++nt)
                bfr[ks][nt] = bbase[(ks * 16 + nt) * 64];

        // A fragments: 8 consecutive x floats per lane, scaled, cvt to f16
        f16x8 af[2][4];
        #pragma unroll
        for (int mt = 0; mt < 2; ++mt) {
            float iv = mt ? iv1 : iv0;
            #pragma unroll
            for (int ks = 0; ks < 4; ++ks) {
                int p  = Wb + mt * 32 + l31 + ks * 16 + lh * 8;
                int pc = p <= L_ - 8 ? p : L_ - 8;   // only invalid windows clamp
                f32x4u v0 = *(const f32x4u*)(xrow + pc);
                f32x4u v1 = *(const f32x4u*)(xrow + pc + 4);
                f16x8 o;
                o[0] = (_Float16)(v0[0] * iv); o[1] = (_Float16)(v0[1] * iv);
                o[2] = (_Float16)(v0[2] * iv); o[3] = (_Float16)(v0[3] * iv);
                o[4] = (_Float16)(v1[0] * iv); o[5] = (_Float16)(v1[1] * iv);
                o[6] = (_Float16)(v1[2] * iv); o[7] = (_Float16)(v1[3] * iv);
                af[mt][ks] = o;
            }
        }

        #pragma unroll
        for (int ks = 0; ks < 4; ++ks)
            #pragma unroll
            for (int nt = 0; nt < 4; ++nt)
                #pragma unroll
                for (int mt = 0; mt < 2; ++mt)
                    acc[mt][nt] = __builtin_amdgcn_mfma_f32_32x32x16_f16(
                        af[mt][ks], bfr[ks][nt], acc[mt][nt], 0, 0, 0);
    }

    // epilogue: relu + max over windows (invalid windows exactly 0).
    // 32x32 C/D: col = lane&31; lane and lane^32 cover the same col.
    #pragma unroll
    for (int nt = 0; nt < 4; ++nt) {
        float m = 0.f;
        #pragma unroll
        for (int mt = 0; mt < 2; ++mt)
            #pragma unroll
            for (int r = 0; r < 16; ++r)
                m = fmaxf(m, acc[mt][nt][r]);
        m = fmaxf(m, __shfl_xor(m, 32));
        if (lane < 32)
            atomicMax((unsigned int*)(out + b * K_ + ng * 256 + nw * 128 + nt * 32 + l31),
                      __float_as_uint(m));
    }
}

extern "C" void kernel_launch(void* const* d_in, const int* in_sizes, int n_in,
                              void* d_out, int out_size, void* d_ws, size_t ws_size,
                              hipStream_t stream) {
    const float* x  = (const float*)d_in[0];   // (32, 8, 2048) fp32
    const float* sh = (const float*)d_in[1];   // (8, 512, 64) fp32
    float* out = (float*)d_out;                // (32, 1, 512) fp32
    _Float16* Bp  = (_Float16*)d_ws;           // 512 KB packed shapelets
    float* invn   = (float*)((char*)d_ws + (size_t)K_ * 512 * sizeof(_Float16)); // 2 MB

    prep_k<<<dim3(384), dim3(256), 0, stream>>>(x, sh, Bp, invn, out);
    mcs_k<<<dim3(16, 2, B_), dim3(256), 0, stream>>>(x, Bp, invn, out);
}